// Round 1
// baseline (6284.460 us; speedup 1.0000x reference)
//
#include <hip/hip_runtime.h>

#define NN 16384
#define NF 512
#define NH 64
#define NC 40
#define KSTEPS 10

typedef __attribute__((ext_vector_type(8))) short short8;
typedef __attribute__((ext_vector_type(4))) float f32x4;

__device__ __forceinline__ unsigned short f2bf(float f) {
    unsigned int u = __float_as_uint(f);
    u += 0x7FFFu + ((u >> 16) & 1u);   // RNE
    return (unsigned short)(u >> 16);
}
__device__ __forceinline__ float bf2f(unsigned short h) {
    return __uint_as_float((unsigned int)h << 16);
}

// ---------------------------------------------------------------------------
// h0 = relu(x @ W1), stored bf16.  Block 256 threads: 32 rows x 64 cols.
// Grid = 16384/32 = 512.
// ---------------------------------------------------------------------------
__global__ __launch_bounds__(256) void h0_kernel(const float* __restrict__ x,
                                                 const float* __restrict__ W1,
                                                 unsigned short* __restrict__ h0h) {
    const int col  = threadIdx.x & 63;
    const int w    = threadIdx.x >> 6;       // 0..3
    const int row0 = blockIdx.x * 32;
    float acc[8];
#pragma unroll
    for (int j = 0; j < 8; ++j) acc[j] = 0.f;
    for (int k = 0; k < NF; ++k) {
        float wv = W1[(size_t)k * NH + col];          // coalesced across wave
#pragma unroll
        for (int j = 0; j < 8; ++j)                   // x load is wave-uniform (broadcast)
            acc[j] = fmaf(x[(size_t)(row0 + w + 4 * j) * NF + k], wv, acc[j]);
    }
#pragma unroll
    for (int j = 0; j < 8; ++j) {
        float v = fmaxf(acc[j], 0.f);
        h0h[(size_t)(row0 + w + 4 * j) * NH + col] = f2bf(v);
    }
}

// ---------------------------------------------------------------------------
// adj fp32 -> bf16 (one pass), grid-stride over float4s.
// ---------------------------------------------------------------------------
__global__ __launch_bounds__(256) void conv_kernel(const float4* __restrict__ adj4,
                                                   ushort4* __restrict__ adjh4,
                                                   long total4) {
    long i = (long)blockIdx.x * blockDim.x + threadIdx.x;
    long stride = (long)gridDim.x * blockDim.x;
    for (; i < total4; i += stride) {
        float4 v = adj4[i];
        ushort4 o;
        o.x = f2bf(v.x); o.y = f2bf(v.y); o.z = f2bf(v.z); o.w = f2bf(v.w);
        adjh4[i] = o;
    }
}

// ---------------------------------------------------------------------------
// One propagation step: xnxt = bf16( 0.9 * adj @ xcur + 0.1 * h0 )
// Block: 256 threads = 4 waves; tile 32 rows x 64 cols; BK = 64.
// Wave (wr,wc): rows 16*wr..+15, cols 32*wc..+31 (2 MFMA n-tiles).
// MFMA layouts (measured, cdna_hip_programming.md §3):
//   A frag: lane l -> row l&15, k = 8*(l>>4)+j  (8 contiguous bf16 = b128)
//   B frag: lane l -> col l&15, k = 8*(l>>4)+j  (B stored transposed in LDS)
//   D:      lane l, reg r -> row 4*(l>>4)+r, col l&15
// ---------------------------------------------------------------------------
template <int ADJBF16>
__global__ __launch_bounds__(256) void step_kernel(const void* __restrict__ adjp,
                                                   const unsigned short* __restrict__ xcur,
                                                   const unsigned short* __restrict__ h0h,
                                                   unsigned short* __restrict__ xnxt) {
    // pitch 72 shorts = 144 B = 9*16 B: keeps b128 alignment, breaks bank powers-of-2
    __shared__ __align__(16) unsigned short AL[32][72];
    __shared__ __align__(16) unsigned short BL[64][72];

    const int tid  = threadIdx.x;
    const int lane = tid & 63;
    const int wid  = tid >> 6;
    const int wr   = wid >> 1;          // 0..1 : row half
    const int wc   = wid & 1;           // 0..1 : col half
    const int row0 = blockIdx.x * 32;

    f32x4 acc0 = {0.f, 0.f, 0.f, 0.f};
    f32x4 acc1 = {0.f, 0.f, 0.f, 0.f};

    const int arow = tid >> 3;          // 0..31
    const int aseg = tid & 7;           // 0..7
    const int bk   = tid >> 4;          // 0..15
    const int bc0  = (tid & 15) * 4;    // 0,4,...,60

    for (int kc = 0; kc < NN / 64; ++kc) {
        const int kb = kc * 64;
        // ---- stage A tile (32 rows x 64 k) into LDS as bf16 ----
        if (ADJBF16) {
            const unsigned short* adjh = (const unsigned short*)adjp;
            short8 v = *(const short8*)&adjh[(size_t)(row0 + arow) * NN + kb + aseg * 8];
            *(short8*)&AL[arow][aseg * 8] = v;
        } else {
            const float* adj = (const float*)adjp;
#pragma unroll
            for (int i = 0; i < 2; ++i) {
                int k = aseg * 4 + 32 * i;
                float4 v = *(const float4*)&adj[(size_t)(row0 + arow) * NN + kb + k];
                ushort4 o;
                o.x = f2bf(v.x); o.y = f2bf(v.y); o.z = f2bf(v.z); o.w = f2bf(v.w);
                *(ushort4*)&AL[arow][k] = o;
            }
        }
        // ---- stage B tile (64 k x 64 cols) TRANSPOSED into LDS ----
#pragma unroll
        for (int i = 0; i < 4; ++i) {
            int k = bk + 16 * i;
            ushort4 v = *(const ushort4*)&xcur[(size_t)(kb + k) * NH + bc0];
            BL[bc0 + 0][k] = v.x;
            BL[bc0 + 1][k] = v.y;
            BL[bc0 + 2][k] = v.z;
            BL[bc0 + 3][k] = v.w;
        }
        __syncthreads();
        // ---- MFMA: 2 k-steps of 32, 2 n-tiles ----
        const int fr = lane & 15;
        const int fg = lane >> 4;
#pragma unroll
        for (int g = 0; g < 2; ++g) {
            short8 a  = *(const short8*)&AL[16 * wr + fr][32 * g + 8 * fg];
            short8 b0 = *(const short8*)&BL[32 * wc + fr][32 * g + 8 * fg];
            short8 b1 = *(const short8*)&BL[32 * wc + 16 + fr][32 * g + 8 * fg];
            acc0 = __builtin_amdgcn_mfma_f32_16x16x32_bf16(a, b0, acc0, 0, 0, 0);
            acc1 = __builtin_amdgcn_mfma_f32_16x16x32_bf16(a, b1, acc1, 0, 0, 0);
        }
        __syncthreads();
    }

    // ---- epilogue: 0.9*acc + 0.1*h0 ----
    const int m0 = 16 * wr + 4 * (lane >> 4);
    const int n0 = 32 * wc + (lane & 15);
#pragma unroll
    for (int r = 0; r < 4; ++r) {
        size_t grow = (size_t)(row0 + m0 + r);
        float h0a = bf2f(h0h[grow * NH + n0]);
        float h0b = bf2f(h0h[grow * NH + n0 + 16]);
        xnxt[grow * NH + n0]      = f2bf(0.9f * acc0[r] + 0.1f * h0a);
        xnxt[grow * NH + n0 + 16] = f2bf(0.9f * acc1[r] + 0.1f * h0b);
    }
}

// ---------------------------------------------------------------------------
// h = x_cl @ W2; out1 = log_softmax(h); out2 = x_cl (fp32).
// One wave per row, 4 rows per block. Grid = 16384/4.
// ---------------------------------------------------------------------------
__global__ __launch_bounds__(256) void final_kernel(const unsigned short* __restrict__ xcl,
                                                    const float* __restrict__ W2,
                                                    float* __restrict__ out_ls,
                                                    float* __restrict__ out_x) {
    const int wid  = threadIdx.x >> 6;
    const int lane = threadIdx.x & 63;
    const size_t row = (size_t)blockIdx.x * 4 + wid;

    float xv = bf2f(xcl[row * NH + lane]);   // lane k holds x_cl[row][k]
    out_x[row * NH + lane] = xv;

    float acc = 0.f;
    for (int k = 0; k < NH; ++k) {
        float xk = __shfl(xv, k, 64);
        float wv = (lane < NC) ? W2[(size_t)k * NC + lane] : 0.f;
        acc = fmaf(xk, wv, acc);
    }
    float h = (lane < NC) ? acc : -__builtin_inff();
    float m = h;
#pragma unroll
    for (int off = 32; off >= 1; off >>= 1) m = fmaxf(m, __shfl_xor(m, off, 64));
    float e = (lane < NC) ? expf(h - m) : 0.f;
    float s = e;
#pragma unroll
    for (int off = 32; off >= 1; off >>= 1) s += __shfl_xor(s, off, 64);
    if (lane < NC) out_ls[row * NC + lane] = (h - m) - logf(s);
}

// ---------------------------------------------------------------------------
extern "C" void kernel_launch(void* const* d_in, const int* in_sizes, int n_in,
                              void* d_out, int out_size, void* d_ws, size_t ws_size,
                              hipStream_t stream) {
    const float* x   = (const float*)d_in[0];
    const float* adj = (const float*)d_in[1];
    const float* W1  = (const float*)d_in[2];
    const float* W2  = (const float*)d_in[3];

    float* out_ls = (float*)d_out;                      // 16384*40 fp32
    float* out_x  = out_ls + (size_t)NN * NC;           // 16384*64 fp32

    const size_t xbytes = (size_t)NN * NH * sizeof(unsigned short);  // 2 MiB
    char* ws = (char*)d_ws;

    unsigned short *h0h, *xa, *xb;
    size_t used;
    if (ws_size >= 3 * xbytes) {
        h0h = (unsigned short*)ws;
        xa  = (unsigned short*)(ws + xbytes);
        xb  = (unsigned short*)(ws + 2 * xbytes);
        used = 3 * xbytes;
    } else {
        // tight-ws fallback: ping-pong in ws, h0 parked in the log_softmax
        // output region (overwritten only by the final kernel, after last use)
        xa  = (unsigned short*)ws;
        xb  = xa + (size_t)NN * NH;
        h0h = (unsigned short*)out_ls;
        used = 2 * xbytes;
    }
    used = (used + 255) & ~(size_t)255;

    unsigned short* adjh = nullptr;
    const size_t adjbytes = (size_t)NN * NN * sizeof(unsigned short); // 512 MiB
    if (ws_size >= used + adjbytes) adjh = (unsigned short*)(ws + used);

    h0_kernel<<<NN / 32, 256, 0, stream>>>(x, W1, h0h);

    if (adjh) {
        long total4 = (long)NN * NN / 4;
        conv_kernel<<<8192, 256, 0, stream>>>((const float4*)adj, (ushort4*)adjh, total4);
    }

    unsigned short* cur = h0h;   // x0 = h0
    unsigned short* nxt = xa;
    for (int s = 0; s < KSTEPS; ++s) {
        if (adjh)
            step_kernel<1><<<NN / 32, 256, 0, stream>>>(adjh, cur, h0h, nxt);
        else
            step_kernel<0><<<NN / 32, 256, 0, stream>>>(adj, cur, h0h, nxt);
        unsigned short* t = (cur == h0h) ? xb : cur;  // after step 1, ping-pong xa/xb
        cur = nxt;
        nxt = t;
    }

    final_kernel<<<NN / 4, 256, 0, stream>>>(cur, W2, out_ls, out_x);
}

// Round 2
// 2551.977 us; speedup vs baseline: 2.4626x; 2.4626x over previous
//
#include <hip/hip_runtime.h>

#define NN 16384
#define NF 512
#define NH 64
#define NC 40
#define KSTEPS 10
#define KSPLIT 8          // waves per block, K-split factor
#define BM 32             // rows per block

typedef __attribute__((ext_vector_type(8))) short short8;
typedef __attribute__((ext_vector_type(4))) float f32x4;

__device__ __forceinline__ unsigned short f2bf(float f) {
    unsigned int u = __float_as_uint(f);
    u += 0x7FFFu + ((u >> 16) & 1u);   // RNE
    return (unsigned short)(u >> 16);
}
__device__ __forceinline__ float bf2f(unsigned short h) {
    return __uint_as_float((unsigned int)h << 16);
}
__device__ __forceinline__ short8 cvt8(float4 f0, float4 f1) {
    short8 r;
    r[0] = (short)f2bf(f0.x); r[1] = (short)f2bf(f0.y);
    r[2] = (short)f2bf(f0.z); r[3] = (short)f2bf(f0.w);
    r[4] = (short)f2bf(f1.x); r[5] = (short)f2bf(f1.y);
    r[6] = (short)f2bf(f1.z); r[7] = (short)f2bf(f1.w);
    return r;
}

// ---------------------------------------------------------------------------
// h0T[c][r] = relu(x @ W1)[r][c]  (bf16, transposed layout)
// Block 256 thr = 4 waves; block covers 64 rows; wave w covers cols w*16..+15.
// x row reads are L1-cached (64 lines live); W1 reads wave-uniform broadcast.
// ---------------------------------------------------------------------------
__global__ __launch_bounds__(256) void h0_kernel(const float* __restrict__ x,
                                                 const float* __restrict__ W1,
                                                 unsigned short* __restrict__ h0T) {
    const int t  = threadIdx.x;
    const int rl = t & 63;
    const int w  = t >> 6;
    const size_t r = (size_t)blockIdx.x * 64 + rl;
    const float* xr = x + r * NF;

    float acc[16];
#pragma unroll
    for (int j = 0; j < 16; ++j) acc[j] = 0.f;

    for (int k = 0; k < NF; ++k) {
        float xv = xr[k];
        const float* wr = W1 + (size_t)k * NH + w * 16;
#pragma unroll
        for (int j = 0; j < 16; ++j) acc[j] = fmaf(xv, wr[j], acc[j]);
    }
#pragma unroll
    for (int j = 0; j < 16; ++j)
        h0T[(size_t)(w * 16 + j) * NN + r] = f2bf(fmaxf(acc[j], 0.f));
}

// ---------------------------------------------------------------------------
// One propagation step in transposed space:
//   xnT[c][r] = bf16( 0.9 * (adj @ x)[r][c] + 0.1 * h0T[c][r] )
// MODE 0: read adj as bf16 (adjh).
// MODE 1: read adj fp32, convert, ALSO store bf16 to adjh_out (fused convert).
// MODE 2: read adj fp32 on the fly (no store) — tight-ws fallback.
//
// Block: 512 thr = 8 waves. Block owns BM=32 rows; wave w owns K-range
// [w*2048, (w+1)*2048). Hot loop is barrier-free: direct per-lane short8
// fragment loads from global (A streams HBM; B = xT is L2-resident).
// Per iter (K=64): 4 A-frag + 8 B-frag loads (12 KB/wave), 16 MFMA.
// End: LDS partial combine (padded, conflict-free) + fused epilogue.
// MFMA layouts (verified r1): A/B lane l -> row/col l&15, k=8*(l>>4)+j;
// D lane l reg r -> row 4*(l>>4)+r, col l&15.
// ---------------------------------------------------------------------------
template <int MODE>
__global__ __launch_bounds__(512, 4) void step_kernel(
        const void* __restrict__ adjp,
        unsigned short* __restrict__ adjh_out,
        const unsigned short* __restrict__ xT,
        const unsigned short* __restrict__ h0T,
        unsigned short* __restrict__ xnT) {
    __shared__ float buf[KSPLIT][BM][65];   // 66,560 B; 65-pad -> conflict-free

    const int t    = threadIdx.x;
    const int l    = t & 63;
    const int w    = t >> 6;                // 0..7 : ksplit id
    const int fr   = l & 15;
    const int fg   = l >> 4;
    const int row0 = blockIdx.x * BM;

    const size_t a0 = (size_t)(row0 + fr) * NN;       // A row (mi=0)
    const size_t a1 = a0 + (size_t)16 * NN;           // A row (mi=1)
    const long   kbase = (long)w * (NN / KSPLIT) + 8 * fg;

    f32x4 acc[2][4];
#pragma unroll
    for (int mi = 0; mi < 2; ++mi)
#pragma unroll
        for (int ni = 0; ni < 4; ++ni) acc[mi][ni] = (f32x4){0.f, 0.f, 0.f, 0.f};

    for (int kk = 0; kk < NN / KSPLIT; kk += 64) {
        const long kb = kbase + kk;
        short8 a[2][2], b[4][2];

        if (MODE == 0) {
            const unsigned short* A = (const unsigned short*)adjp;
#pragma unroll
            for (int h = 0; h < 2; ++h) {
                a[0][h] = *(const short8*)&A[a0 + kb + 32 * h];
                a[1][h] = *(const short8*)&A[a1 + kb + 32 * h];
            }
        } else {
            const float* A = (const float*)adjp;
#pragma unroll
            for (int mi = 0; mi < 2; ++mi) {
                const size_t ab = (mi ? a1 : a0);
#pragma unroll
                for (int h = 0; h < 2; ++h) {
                    float4 f0 = *(const float4*)&A[ab + kb + 32 * h];
                    float4 f1 = *(const float4*)&A[ab + kb + 32 * h + 4];
                    a[mi][h] = cvt8(f0, f1);
                    if (MODE == 1)
                        *(short8*)&adjh_out[ab + kb + 32 * h] = a[mi][h];
                }
            }
        }
#pragma unroll
        for (int ni = 0; ni < 4; ++ni)
#pragma unroll
            for (int h = 0; h < 2; ++h)
                b[ni][h] = *(const short8*)&xT[(size_t)(16 * ni + fr) * NN + kb + 32 * h];

#pragma unroll
        for (int mi = 0; mi < 2; ++mi)
#pragma unroll
            for (int ni = 0; ni < 4; ++ni)
#pragma unroll
                for (int h = 0; h < 2; ++h)
                    acc[mi][ni] = __builtin_amdgcn_mfma_f32_16x16x32_bf16(
                        a[mi][h], b[ni][h], acc[mi][ni], 0, 0, 0);
    }

    // ---- write per-wave partials to LDS ----
#pragma unroll
    for (int mi = 0; mi < 2; ++mi)
#pragma unroll
        for (int ni = 0; ni < 4; ++ni)
#pragma unroll
            for (int r = 0; r < 4; ++r)
                buf[w][16 * mi + 4 * fg + r][16 * ni + fr] = acc[mi][ni][r];
    __syncthreads();

    // ---- reduce 8 partials + epilogue; thread t -> col t>>3, rows 4*(t&7).. ----
    const int col = t >> 3;
    const int rb  = 4 * (t & 7);
    float s0 = 0.f, s1 = 0.f, s2 = 0.f, s3 = 0.f;
#pragma unroll
    for (int ww = 0; ww < KSPLIT; ++ww) {
        s0 += buf[ww][rb + 0][col];
        s1 += buf[ww][rb + 1][col];
        s2 += buf[ww][rb + 2][col];
        s3 += buf[ww][rb + 3][col];
    }
    const size_t base = (size_t)col * NN + row0 + rb;
    ushort4 h4 = *(const ushort4*)&h0T[base];
    ushort4 o;
    o.x = f2bf(0.9f * s0 + 0.1f * bf2f(h4.x));
    o.y = f2bf(0.9f * s1 + 0.1f * bf2f(h4.y));
    o.z = f2bf(0.9f * s2 + 0.1f * bf2f(h4.z));
    o.w = f2bf(0.9f * s3 + 0.1f * bf2f(h4.w));
    *(ushort4*)&xnT[base] = o;
}

// ---------------------------------------------------------------------------
// Final: h = x_cl @ W2; out_ls = log_softmax(h); out_x = x_cl fp32 row-major.
// Block 256 thr covers 64 rows; LDS tile detransposes xT; logits per-thread.
// ---------------------------------------------------------------------------
__global__ __launch_bounds__(256) void final_kernel(const unsigned short* __restrict__ xT,
                                                    const float* __restrict__ W2,
                                                    float* __restrict__ out_ls,
                                                    float* __restrict__ out_x) {
    __shared__ float LS[64][65];
    const int t  = threadIdx.x;
    const int rl = t & 63;
    const int w  = t >> 6;
    const int r0 = blockIdx.x * 64;

    // load tile: coalesced along rows of xT
#pragma unroll
    for (int j = 0; j < 16; ++j) {
        int c = w * 16 + j;
        LS[c][rl] = bf2f(xT[(size_t)c * NN + r0 + rl]);
    }
    __syncthreads();

    // out_x (row-major fp32), coalesced; LDS reads conflict-free (65-pad)
#pragma unroll
    for (int k2 = 0; k2 < 16; ++k2) {
        int idx = k2 * 256 + t;
        int row = idx >> 6, col = idx & 63;
        out_x[(size_t)(r0 + row) * NH + col] = LS[col][row];
    }

    // logits + log_softmax: one thread per row (threads 0..63)
    float acc[NC];
    if (t < 64) {
#pragma unroll
        for (int j = 0; j < NC; ++j) acc[j] = 0.f;
        for (int c = 0; c < NH; ++c) {
            float xv = LS[c][t];
            const float* wr = W2 + (size_t)c * NC;
#pragma unroll
            for (int j = 0; j < NC; ++j) acc[j] = fmaf(xv, wr[j], acc[j]);
        }
        float m = acc[0];
#pragma unroll
        for (int j = 1; j < NC; ++j) m = fmaxf(m, acc[j]);
        float s = 0.f;
#pragma unroll
        for (int j = 0; j < NC; ++j) s += expf(acc[j] - m);
        float lg = m + logf(s);
#pragma unroll
        for (int j = 0; j < NC; ++j) acc[j] -= lg;
    }
    __syncthreads();               // all LS reads done
    if (t < 64) {
#pragma unroll
        for (int j = 0; j < NC; ++j) LS[t][j] = acc[j];
    }
    __syncthreads();
    for (int i = t; i < 64 * NC; i += 256) {
        int row = i / NC, j = i - row * NC;
        out_ls[(size_t)r0 * NC + i] = LS[row][j];
    }
}

// ---------------------------------------------------------------------------
extern "C" void kernel_launch(void* const* d_in, const int* in_sizes, int n_in,
                              void* d_out, int out_size, void* d_ws, size_t ws_size,
                              hipStream_t stream) {
    const float* x   = (const float*)d_in[0];
    const float* adj = (const float*)d_in[1];
    const float* W1  = (const float*)d_in[2];
    const float* W2  = (const float*)d_in[3];

    float* out_ls = (float*)d_out;                      // 16384*40 fp32
    float* out_x  = out_ls + (size_t)NN * NC;           // 16384*64 fp32

    const size_t xbytes = (size_t)NN * NH * sizeof(unsigned short);  // 2 MiB
    char* ws = (char*)d_ws;

    unsigned short *h0T, *xa, *xb;
    size_t used;
    if (ws_size >= 3 * xbytes) {
        h0T = (unsigned short*)ws;
        xa  = (unsigned short*)(ws + xbytes);
        xb  = (unsigned short*)(ws + 2 * xbytes);
        used = 3 * xbytes;
    } else {
        // tight-ws fallback: h0T parked in out_ls (fully overwritten by
        // final_kernel only after h0T's last use)
        xa  = (unsigned short*)ws;
        xb  = xa + (size_t)NN * NH;
        h0T = (unsigned short*)out_ls;
        used = 2 * xbytes;
    }
    used = (used + 255) & ~(size_t)255;

    unsigned short* adjh = nullptr;
    const size_t adjbytes = (size_t)NN * NN * sizeof(unsigned short); // 512 MiB
    if (ws_size >= used + adjbytes) adjh = (unsigned short*)(ws + used);

    h0_kernel<<<NN / 64, 256, 0, stream>>>(x, W1, h0T);

    unsigned short* cur = h0T;   // x0 = h0
    unsigned short* nxt = xa;
    for (int s = 0; s < KSTEPS; ++s) {
        if (adjh) {
            if (s == 0)
                step_kernel<1><<<NN / BM, 512, 0, stream>>>(adj, adjh, cur, h0T, nxt);
            else
                step_kernel<0><<<NN / BM, 512, 0, stream>>>(adjh, nullptr, cur, h0T, nxt);
        } else {
            step_kernel<2><<<NN / BM, 512, 0, stream>>>(adj, nullptr, cur, h0T, nxt);
        }
        unsigned short* tswap = (cur == h0T) ? xb : cur;
        cur = nxt;
        nxt = tswap;
    }

    final_kernel<<<NN / 64, 256, 0, stream>>>(cur, W2, out_ls, out_x);
}

// Round 3
// 1916.716 us; speedup vs baseline: 3.2788x; 1.3314x over previous
//
#include <hip/hip_runtime.h>

#define NN 16384
#define NF 512
#define NH 64
#define NC 40
#define KSTEPS 10
#define KSPLIT 8          // waves per block = K-split factor
#define BM 32             // rows per block

typedef __attribute__((ext_vector_type(8))) short short8;
typedef __attribute__((ext_vector_type(4))) float f32x4;

__device__ __forceinline__ unsigned short f2bf(float f) {
    unsigned int u = __float_as_uint(f);
    u += 0x7FFFu + ((u >> 16) & 1u);   // RNE
    return (unsigned short)(u >> 16);
}
__device__ __forceinline__ float bf2f(unsigned short h) {
    return __uint_as_float((unsigned int)h << 16);
}
__device__ __forceinline__ short8 cvt8(float4 f0, float4 f1) {
    short8 r;
    r[0] = (short)f2bf(f0.x); r[1] = (short)f2bf(f0.y);
    r[2] = (short)f2bf(f0.z); r[3] = (short)f2bf(f0.w);
    r[4] = (short)f2bf(f1.x); r[5] = (short)f2bf(f1.y);
    r[6] = (short)f2bf(f1.z); r[7] = (short)f2bf(f1.w);
    return r;
}

// ---------------------------------------------------------------------------
// h0T[c][r] = relu(x @ W1)[r][c]  (bf16, transposed layout)
// ---------------------------------------------------------------------------
__global__ __launch_bounds__(256) void h0_kernel(const float* __restrict__ x,
                                                 const float* __restrict__ W1,
                                                 unsigned short* __restrict__ h0T) {
    const int t  = threadIdx.x;
    const int rl = t & 63;
    const int w  = t >> 6;
    const size_t r = (size_t)blockIdx.x * 64 + rl;
    const float* xr = x + r * NF;

    float acc[16];
#pragma unroll
    for (int j = 0; j < 16; ++j) acc[j] = 0.f;

    for (int k = 0; k < NF; k += 4) {
        float4 xv = *(const float4*)&xr[k];
#pragma unroll
        for (int i = 0; i < 4; ++i) {
            float xs = (i == 0) ? xv.x : (i == 1) ? xv.y : (i == 2) ? xv.z : xv.w;
            const float* wr = W1 + (size_t)(k + i) * NH + w * 16;
#pragma unroll
            for (int j = 0; j < 16; ++j) acc[j] = fmaf(xs, wr[j], acc[j]);
        }
    }
#pragma unroll
    for (int j = 0; j < 16; ++j)
        h0T[(size_t)(w * 16 + j) * NN + r] = f2bf(fmaxf(acc[j], 0.f));
}

// ---------------------------------------------------------------------------
// Shared tail: combine 8 per-wave K-partials in LDS, fuse 0.9*s + 0.1*h0T,
// store bf16 to xnT (transposed layout). buf padded to 65 -> conflict-free.
// ---------------------------------------------------------------------------
__device__ __forceinline__ void finish_block(float buf[KSPLIT][BM][65],
                                             const f32x4 (&acc)[2][4],
                                             int t, int l, int w, int row0,
                                             const unsigned short* __restrict__ h0T,
                                             unsigned short* __restrict__ xnT) {
    const int fr = l & 15;
    const int fg = l >> 4;
#pragma unroll
    for (int mi = 0; mi < 2; ++mi)
#pragma unroll
        for (int ni = 0; ni < 4; ++ni)
#pragma unroll
            for (int r = 0; r < 4; ++r)
                buf[w][16 * mi + 4 * fg + r][16 * ni + fr] = acc[mi][ni][r];
    __syncthreads();

    const int col = t >> 3;
    const int rb  = 4 * (t & 7);
    float s0 = 0.f, s1 = 0.f, s2 = 0.f, s3 = 0.f;
#pragma unroll
    for (int ww = 0; ww < KSPLIT; ++ww) {
        s0 += buf[ww][rb + 0][col];
        s1 += buf[ww][rb + 1][col];
        s2 += buf[ww][rb + 2][col];
        s3 += buf[ww][rb + 3][col];
    }
    const size_t base = (size_t)col * NN + row0 + rb;
    ushort4 h4 = *(const ushort4*)&h0T[base];
    ushort4 o;
    o.x = f2bf(0.9f * s0 + 0.1f * bf2f(h4.x));
    o.y = f2bf(0.9f * s1 + 0.1f * bf2f(h4.y));
    o.z = f2bf(0.9f * s2 + 0.1f * bf2f(h4.z));
    o.w = f2bf(0.9f * s3 + 0.1f * bf2f(h4.w));
    *(ushort4*)&xnT[base] = o;
}

// ---------------------------------------------------------------------------
// Step 0 (fused): read adj fp32 (row-major), convert to bf16, MFMA, and store
// the bf16 fragments into the TILED layout adjT[rt][kt][h][lane][8]:
//   flat short idx = ((rt*256 + kt)*2 + h)*512 + lane*8 + j
//   element        = adj[rt*16 + (lane&15)][kt*64 + 32*h + 8*(lane>>4) + j]
// so steps 1..9 read A as wave-contiguous 1 KB chunks (DRAM-sequential).
// ---------------------------------------------------------------------------
__global__ __launch_bounds__(512, 2) void step0_kernel(
        const float* __restrict__ adj,
        unsigned short* __restrict__ adjT,
        const unsigned short* __restrict__ xT,
        const unsigned short* __restrict__ h0T,
        unsigned short* __restrict__ xnT) {
    __shared__ float buf[KSPLIT][BM][65];

    const int t    = threadIdx.x;
    const int l    = t & 63;
    const int w    = t >> 6;
    const int fr   = l & 15;
    const int fg   = l >> 4;
    const int row0 = blockIdx.x * BM;

    const size_t a0 = (size_t)(row0 + fr) * NN;
    const size_t a1 = a0 + (size_t)16 * NN;
    const long   kbase = (long)w * (NN / KSPLIT) + 8 * fg;

    f32x4 acc[2][4];
#pragma unroll
    for (int mi = 0; mi < 2; ++mi)
#pragma unroll
        for (int ni = 0; ni < 4; ++ni) acc[mi][ni] = (f32x4){0.f, 0.f, 0.f, 0.f};

    for (int kk = 0; kk < NN / KSPLIT; kk += 64) {
        const long kb    = kbase + kk;
        const size_t ktile = (size_t)w * 32 + (kk >> 6);
        short8 a[2][2], b[4][2];

#pragma unroll
        for (int mi = 0; mi < 2; ++mi) {
            const size_t ab = (mi ? a1 : a0);
#pragma unroll
            for (int h = 0; h < 2; ++h) {
                float4 f0 = *(const float4*)&adj[ab + kb + 32 * h];
                float4 f1 = *(const float4*)&adj[ab + kb + 32 * h + 4];
                a[mi][h] = cvt8(f0, f1);
                const size_t st = ((size_t)(2 * blockIdx.x + mi) * 256 + ktile) * 1024
                                  + (size_t)h * 512 + (size_t)l * 8;
                *(short8*)&adjT[st] = a[mi][h];
            }
        }
#pragma unroll
        for (int ni = 0; ni < 4; ++ni)
#pragma unroll
            for (int h = 0; h < 2; ++h)
                b[ni][h] = *(const short8*)&xT[(size_t)(16 * ni + fr) * NN + kb + 32 * h];

#pragma unroll
        for (int mi = 0; mi < 2; ++mi)
#pragma unroll
            for (int ni = 0; ni < 4; ++ni)
#pragma unroll
                for (int h = 0; h < 2; ++h)
                    acc[mi][ni] = __builtin_amdgcn_mfma_f32_16x16x32_bf16(
                        a[mi][h], b[ni][h], acc[mi][ni], 0, 0, 0);
    }
    finish_block(buf, acc, t, l, w, row0, h0T, xnT);
}

// ---------------------------------------------------------------------------
// Steps 1..9: A from tiled adjT — per wave, two purely sequential streams,
// 1 KB fully-coalesced loads (per-lane offset = l*16 B). Barrier-free K loop.
// ---------------------------------------------------------------------------
__global__ __launch_bounds__(512, 4) void stept_kernel(
        const unsigned short* __restrict__ adjT,
        const unsigned short* __restrict__ xT,
        const unsigned short* __restrict__ h0T,
        unsigned short* __restrict__ xnT) {
    __shared__ float buf[KSPLIT][BM][65];

    const int t    = threadIdx.x;
    const int l    = t & 63;
    const int w    = t >> 6;
    const int fr   = l & 15;
    const int row0 = blockIdx.x * BM;
    const long kbase = (long)w * (NN / KSPLIT) + 8 * (l >> 4);

    const unsigned short* At0 = adjT
        + ((size_t)(2 * blockIdx.x) * 256 + (size_t)w * 32) * 1024 + (size_t)l * 8;
    const unsigned short* At1 = At0 + (size_t)256 * 1024;   // rt+1

    f32x4 acc[2][4];
#pragma unroll
    for (int mi = 0; mi < 2; ++mi)
#pragma unroll
        for (int ni = 0; ni < 4; ++ni) acc[mi][ni] = (f32x4){0.f, 0.f, 0.f, 0.f};

    for (int kk = 0; kk < NN / KSPLIT; kk += 64) {
        const long kb = kbase + kk;
        short8 a[2][2], b[4][2];

        a[0][0] = *(const short8*)(At0);
        a[0][1] = *(const short8*)(At0 + 512);
        a[1][0] = *(const short8*)(At1);
        a[1][1] = *(const short8*)(At1 + 512);
        At0 += 1024;
        At1 += 1024;

#pragma unroll
        for (int ni = 0; ni < 4; ++ni)
#pragma unroll
            for (int h = 0; h < 2; ++h)
                b[ni][h] = *(const short8*)&xT[(size_t)(16 * ni + fr) * NN + kb + 32 * h];

#pragma unroll
        for (int mi = 0; mi < 2; ++mi)
#pragma unroll
            for (int ni = 0; ni < 4; ++ni)
#pragma unroll
                for (int h = 0; h < 2; ++h)
                    acc[mi][ni] = __builtin_amdgcn_mfma_f32_16x16x32_bf16(
                        a[mi][h], b[ni][h], acc[mi][ni], 0, 0, 0);
    }
    finish_block(buf, acc, t, l, w, row0, h0T, xnT);
}

// ---------------------------------------------------------------------------
// Fallback (tiny workspace): fp32 adj on the fly, untiled. Correct but slow.
// ---------------------------------------------------------------------------
__global__ __launch_bounds__(512, 4) void stepf_kernel(
        const float* __restrict__ adj,
        const unsigned short* __restrict__ xT,
        const unsigned short* __restrict__ h0T,
        unsigned short* __restrict__ xnT) {
    __shared__ float buf[KSPLIT][BM][65];

    const int t    = threadIdx.x;
    const int l    = t & 63;
    const int w    = t >> 6;
    const int fr   = l & 15;
    const int row0 = blockIdx.x * BM;

    const size_t a0 = (size_t)(row0 + fr) * NN;
    const size_t a1 = a0 + (size_t)16 * NN;
    const long   kbase = (long)w * (NN / KSPLIT) + 8 * (l >> 4);

    f32x4 acc[2][4];
#pragma unroll
    for (int mi = 0; mi < 2; ++mi)
#pragma unroll
        for (int ni = 0; ni < 4; ++ni) acc[mi][ni] = (f32x4){0.f, 0.f, 0.f, 0.f};

    for (int kk = 0; kk < NN / KSPLIT; kk += 64) {
        const long kb = kbase + kk;
        short8 a[2][2], b[4][2];
#pragma unroll
        for (int mi = 0; mi < 2; ++mi) {
            const size_t ab = (mi ? a1 : a0);
#pragma unroll
            for (int h = 0; h < 2; ++h) {
                float4 f0 = *(const float4*)&adj[ab + kb + 32 * h];
                float4 f1 = *(const float4*)&adj[ab + kb + 32 * h + 4];
                a[mi][h] = cvt8(f0, f1);
            }
        }
#pragma unroll
        for (int ni = 0; ni < 4; ++ni)
#pragma unroll
            for (int h = 0; h < 2; ++h)
                b[ni][h] = *(const short8*)&xT[(size_t)(16 * ni + fr) * NN + kb + 32 * h];
#pragma unroll
        for (int mi = 0; mi < 2; ++mi)
#pragma unroll
            for (int ni = 0; ni < 4; ++ni)
#pragma unroll
                for (int h = 0; h < 2; ++h)
                    acc[mi][ni] = __builtin_amdgcn_mfma_f32_16x16x32_bf16(
                        a[mi][h], b[ni][h], acc[mi][ni], 0, 0, 0);
    }
    finish_block(buf, acc, t, l, w, row0, h0T, xnT);
}

// ---------------------------------------------------------------------------
// Final: h = x_cl @ W2; out_ls = log_softmax(h); out_x = x_cl fp32 row-major.
// ---------------------------------------------------------------------------
__global__ __launch_bounds__(256) void final_kernel(const unsigned short* __restrict__ xT,
                                                    const float* __restrict__ W2,
                                                    float* __restrict__ out_ls,
                                                    float* __restrict__ out_x) {
    __shared__ float LS[64][65];
    const int t  = threadIdx.x;
    const int rl = t & 63;
    const int w  = t >> 6;
    const int r0 = blockIdx.x * 64;

#pragma unroll
    for (int j = 0; j < 16; ++j) {
        int c = w * 16 + j;
        LS[c][rl] = bf2f(xT[(size_t)c * NN + r0 + rl]);
    }
    __syncthreads();

#pragma unroll
    for (int k2 = 0; k2 < 16; ++k2) {
        int idx = k2 * 256 + t;
        int row = idx >> 6, col = idx & 63;
        out_x[(size_t)(r0 + row) * NH + col] = LS[col][row];
    }

    float acc[NC];
    if (t < 64) {
#pragma unroll
        for (int j = 0; j < NC; ++j) acc[j] = 0.f;
        for (int c = 0; c < NH; ++c) {
            float xv = LS[c][t];
            const float* wr = W2 + (size_t)c * NC;
#pragma unroll
            for (int j = 0; j < NC; ++j) acc[j] = fmaf(xv, wr[j], acc[j]);
        }
        float m = acc[0];
#pragma unroll
        for (int j = 1; j < NC; ++j) m = fmaxf(m, acc[j]);
        float s = 0.f;
#pragma unroll
        for (int j = 0; j < NC; ++j) s += expf(acc[j] - m);
        float lg = m + logf(s);
#pragma unroll
        for (int j = 0; j < NC; ++j) acc[j] -= lg;
    }
    __syncthreads();
    if (t < 64) {
#pragma unroll
        for (int j = 0; j < NC; ++j) LS[t][j] = acc[j];
    }
    __syncthreads();
    for (int i = t; i < 64 * NC; i += 256) {
        int row = i / NC, j = i - row * NC;
        out_ls[(size_t)r0 * NC + i] = LS[row][j];
    }
}

// ---------------------------------------------------------------------------
extern "C" void kernel_launch(void* const* d_in, const int* in_sizes, int n_in,
                              void* d_out, int out_size, void* d_ws, size_t ws_size,
                              hipStream_t stream) {
    const float* x   = (const float*)d_in[0];
    const float* adj = (const float*)d_in[1];
    const float* W1  = (const float*)d_in[2];
    const float* W2  = (const float*)d_in[3];

    float* out_ls = (float*)d_out;                      // 16384*40 fp32
    float* out_x  = out_ls + (size_t)NN * NC;           // 16384*64 fp32

    const size_t xbytes = (size_t)NN * NH * sizeof(unsigned short);  // 2 MiB
    char* ws = (char*)d_ws;

    unsigned short *h0T, *xa, *xb;
    size_t used;
    if (ws_size >= 3 * xbytes) {
        h0T = (unsigned short*)ws;
        xa  = (unsigned short*)(ws + xbytes);
        xb  = (unsigned short*)(ws + 2 * xbytes);
        used = 3 * xbytes;
    } else {
        xa  = (unsigned short*)ws;
        xb  = xa + (size_t)NN * NH;
        h0T = (unsigned short*)out_ls;   // overwritten only by final_kernel
        used = 2 * xbytes;
    }
    used = (used + 255) & ~(size_t)255;

    unsigned short* adjT = nullptr;
    const size_t adjbytes = (size_t)NN * NN * sizeof(unsigned short); // 512 MiB
    if (ws_size >= used + adjbytes) adjT = (unsigned short*)(ws + used);

    h0_kernel<<<NN / 64, 256, 0, stream>>>(x, W1, h0T);

    unsigned short* cur = h0T;   // x0 = h0
    unsigned short* nxt = xa;
    for (int s = 0; s < KSTEPS; ++s) {
        if (adjT) {
            if (s == 0)
                step0_kernel<<<NN / BM, 512, 0, stream>>>(adj, adjT, cur, h0T, nxt);
            else
                stept_kernel<<<NN / BM, 512, 0, stream>>>(adjT, cur, h0T, nxt);
        } else {
            stepf_kernel<<<NN / BM, 512, 0, stream>>>(adj, cur, h0T, nxt);
        }
        unsigned short* tswap = (cur == h0T) ? xb : cur;
        cur = nxt;
        nxt = tswap;
    }

    final_kernel<<<NN / 64, 256, 0, stream>>>(cur, W2, out_ls, out_x);
}